// Round 10
// baseline (72.077 us; speedup 1.0000x reference)
//
#include <hip/hip_runtime.h>

// MoV3D: 3D local attention, window +-2 (125 offsets), B=2 C=32 H=W=D=48, 4 heads x 8 ch.
// ROUND 10: occupancy-first. Tile (4x,8y,8z), 1 voxel/thread, 256 threads.
// Halo 8x12x12 = 1152 LDS lines (16B = all 8 head channels, fp16 pairs) = 18 KB
// -> 8 blocks/CU resident (launch_bounds(256,8)), 32-wave cap. Grid 3456 = 13.5
// blocks/CU -> rounds 8 + 5.5 (time-avg occupancy ~84% vs round-9's measured 44%:
// 6.75/CU over 5-resident quantized to (5 + 1.75)/2 = 42% -- the measured wall).
// Line = lx*144 + lz*12 + ly: ly coeff 1 -> stride-8 lane phases (r8-verified) hit
// 8 distinct bank groups -> conflict-free b128 reads; 5 uniform taps per (dx,dy).
// Scores via v_dot2_f32_f16, log2 domain -> 1-instr exp2; z-validity folded into
// dot-chain seed (0 / -16384 -> exp2==0 == reference -1000 underflow); xy-mask on
// aggregates. Staged addresses only need IN-BOUNDS (flat clamp).
// RULE-#20: no local arrays; every per-thread value is a named scalar.

#define S_PLANE 2304      // 48*48
#define S_CHAN 110592     // 48*48*48
#define TOTAL  7077888    // 2*32*S_CHAN

typedef _Float16 h2 __attribute__((ext_vector_type(2)));

__device__ __forceinline__ float dot2(h2 a, h2 b, float c) {
#if __has_builtin(__builtin_amdgcn_fdot2)
    return __builtin_amdgcn_fdot2(a, b, c, false);
#else
    return fmaf((float)a[0], (float)b[0], fmaf((float)a[1], (float)b[1], c));
#endif
}

__device__ __forceinline__ h2 bc(unsigned w) { return __builtin_bit_cast(h2, w); }
__device__ __forceinline__ unsigned pk(float a, float b) {
    return __builtin_bit_cast(unsigned, h2{(_Float16)a, (_Float16)b});
}

__global__ __launch_bounds__(256, 8) void mov3d_kernel(
    const float* __restrict__ xq, const float* __restrict__ xk,
    float* __restrict__ out)
{
    __shared__ __align__(16) unsigned kw[4608];   // 1152 lines * 16 B = 18 KB

    const int tid = threadIdx.x;
    const int tz8 = tid & 7;          // z within tile
    const int ty = (tid >> 3) & 7;    // y within tile
    const int tx = tid >> 6;          // x within tile (wave index)

    int blk = blockIdx.x;             // 3456 = 4(h) * [2(b)*12(xt)*6(yt)*6(zt)]
    const int h = blk / 864;
    int rem = blk - h * 864;
    const int zt = rem % 6;  rem /= 6;
    const int yt = rem % 6;  rem /= 6;
    const int xt = rem % 12;
    const int b  = rem / 12;

    const int x0 = xt * 4, y0 = yt * 8, z0 = zt * 8;
    const int x = x0 + tx, y = y0 + ty, z = z0 + tz8;
    const unsigned sp = (unsigned)(x * S_PLANE + y * 48 + z);
    const int bbase = b * (32 * S_CHAN);

    // hd^-0.5 * log2(e): scores in log2 domain
    const float QSCALE = 0.35355339059327373f * 1.4426950408889634f;

    // ---- q: 8 channels (c = 4k+h) at this voxel; pack into 4 fp16 pairs ----
    const float qf0 = xq[(unsigned)(bbase + (h     ) * S_CHAN) + sp];
    const float qf1 = xq[(unsigned)(bbase + (h +  4) * S_CHAN) + sp];
    const float qf2 = xq[(unsigned)(bbase + (h +  8) * S_CHAN) + sp];
    const float qf3 = xq[(unsigned)(bbase + (h + 12) * S_CHAN) + sp];
    const float qf4 = xq[(unsigned)(bbase + (h + 16) * S_CHAN) + sp];
    const float qf5 = xq[(unsigned)(bbase + (h + 20) * S_CHAN) + sp];
    const float qf6 = xq[(unsigned)(bbase + (h + 24) * S_CHAN) + sp];
    const float qf7 = xq[(unsigned)(bbase + (h + 28) * S_CHAN) + sp];
    const h2 qA0 = h2{(_Float16)(qf0 * QSCALE), (_Float16)(qf1 * QSCALE)};
    const h2 qA1 = h2{(_Float16)(qf2 * QSCALE), (_Float16)(qf3 * QSCALE)};
    const h2 qA2 = h2{(_Float16)(qf4 * QSCALE), (_Float16)(qf5 * QSCALE)};
    const h2 qA3 = h2{(_Float16)(qf6 * QSCALE), (_Float16)(qf7 * QSCALE)};

    // ---- stage K halo: thread u covers z-pair (2*lz2, 2*lz2+1) at (lx,ly) ----
    // u in [0,576): lx = u/72, r = u%72, lz2 = r/12, ly = r%12
    // writes lines L0 = lx*144 + lz2*24 + ly (lz even) and L0+12 (lz odd)
    const int sBase = bbase + h * S_CHAN;
#define STAGE_GROUP(G) do {                                                   \
        const int u = (G) * 256 + tid;                                        \
        if ((G) < 2 || tid < 64) {                                            \
            const int lx  = u / 72;                                           \
            const int r   = u - lx * 72;                                      \
            const int lz2 = r / 12;                                           \
            const int ly  = r - lz2 * 12;                                     \
            const int f = sBase + (x0 - 2 + lx) * S_PLANE                     \
                        + (y0 - 2 + ly) * 48 + (z0 - 2 + 2 * lz2);            \
            const int a0 = min(max(f,               0), TOTAL - 2);           \
            const int a1 = min(max(f +  8 * S_CHAN, 0), TOTAL - 2);           \
            const int a2 = min(max(f + 16 * S_CHAN, 0), TOTAL - 2);           \
            const int a3 = min(max(f + 24 * S_CHAN, 0), TOTAL - 2);           \
            const int c0 = min(max(f +  4 * S_CHAN, 0), TOTAL - 2);           \
            const int c1 = min(max(f + 12 * S_CHAN, 0), TOTAL - 2);           \
            const int c2 = min(max(f + 20 * S_CHAN, 0), TOTAL - 2);           \
            const int c3 = min(max(f + 28 * S_CHAN, 0), TOTAL - 2);           \
            const float2 vA0 = *(const float2*)&xk[a0];                       \
            const float2 vA1 = *(const float2*)&xk[a1];                       \
            const float2 vA2 = *(const float2*)&xk[a2];                       \
            const float2 vA3 = *(const float2*)&xk[a3];                       \
            const float2 vB0 = *(const float2*)&xk[c0];                       \
            const float2 vB1 = *(const float2*)&xk[c1];                       \
            const float2 vB2 = *(const float2*)&xk[c2];                       \
            const float2 vB3 = *(const float2*)&xk[c3];                       \
            const uint4 W0 = {pk(vA0.x, vB0.x), pk(vA1.x, vB1.x),             \
                              pk(vA2.x, vB2.x), pk(vA3.x, vB3.x)};            \
            const uint4 W1 = {pk(vA0.y, vB0.y), pk(vA1.y, vB1.y),             \
                              pk(vA2.y, vB2.y), pk(vA3.y, vB3.y)};            \
            const int L0 = lx * 144 + lz2 * 24 + ly;                          \
            *(uint4*)&kw[L0 * 4] = W0;                                        \
            *(uint4*)&kw[(L0 + 12) * 4] = W1;                                 \
        }                                                                     \
    } while (0)
    STAGE_GROUP(0);
    STAGE_GROUP(1);
    STAGE_GROUP(2);
#undef STAGE_GROUP
    __syncthreads();   // single barrier

    // z-validity seeds: slot U covers abs z-2+U; invalid -> exp2(dot-16384) == 0
    const float NEG = -16384.f;
    const float zs0 = ((unsigned)(z - 2) < 48u) ? 0.f : NEG;
    const float zs1 = ((unsigned)(z - 1) < 48u) ? 0.f : NEG;
    const float zs2 = 0.f;                           // z in [0,48)
    const float zs3 = ((unsigned)(z + 1) < 48u) ? 0.f : NEG;
    const float zs4 = ((unsigned)(z + 2) < 48u) ? 0.f : NEG;

    float l = 0.f, ax = 0.f, ay = 0.f, az = 0.f;

#define SCORE(T, SEED) \
    dot2(qA0, bc((T).x), dot2(qA1, bc((T).y), dot2(qA2, bc((T).z), dot2(qA3, bc((T).w), (SEED)))))

    __builtin_amdgcn_s_setprio(1);
#pragma unroll
    for (int dx = -2; dx <= 2; ++dx) {
        const bool vx = (unsigned)(x + dx) < 48u;
        const float fdx = (float)dx;
#pragma unroll
        for (int dy = -2; dy <= 2; ++dy) {
            const bool vxy = vx && ((unsigned)(y + dy) < 48u);
            const float fdy = (float)dy;
            // base line: taps at line m + U*12, U = 0..4 (lz = tz8 + U)
            const unsigned* pb = kw
                + ((tx + 2 + dx) * 144 + tz8 * 12 + (ty + 2 + dy)) * 4;

            const uint4 T0 = *(const uint4*)(pb);
            const uint4 T1 = *(const uint4*)(pb + 48);
            const uint4 T2 = *(const uint4*)(pb + 96);
            const uint4 T3 = *(const uint4*)(pb + 144);
            const uint4 T4 = *(const uint4*)(pb + 192);

            const float e0 = exp2f(SCORE(T0, zs0));
            const float e1 = exp2f(SCORE(T1, zs1));
            const float e2 = exp2f(SCORE(T2, zs2));
            const float e3 = exp2f(SCORE(T3, zs3));
            const float e4 = exp2f(SCORE(T4, zs4));

            float ws  = ((e0 + e1) + (e2 + e3)) + e4;
            float azP = fmaf(2.f, e4 - e0, e3 - e1);

            // xy-mask applied once on the aggregates (shared by all 5 z-taps)
            ws  = vxy ? ws  : 0.f;
            azP = vxy ? azP : 0.f;

            l += ws;
            ax = fmaf(fdx, ws, ax);
            ay = fmaf(fdy, ws, ay);
            az += azP;
        }
    }
    __builtin_amdgcn_s_setprio(0);
#undef SCORE

    const float r = 0.25f / l;
    const unsigned ob = (unsigned)b * (3 * S_CHAN);
    atomicAdd(&out[ob + 0u * S_CHAN + sp], ax * r);
    atomicAdd(&out[ob + 1u * S_CHAN + sp], ay * r);
    atomicAdd(&out[ob + 2u * S_CHAN + sp], az * r);
}

extern "C" void kernel_launch(void* const* d_in, const int* in_sizes, int n_in,
                              void* d_out, int out_size, void* d_ws, size_t ws_size,
                              hipStream_t stream) {
    const float* xq = (const float*)d_in[0];
    const float* xk = (const float*)d_in[1];
    float* out = (float*)d_out;
    // zero output (heads accumulate via atomicAdd); memset node is graph-capturable
    hipMemsetAsync(out, 0, (size_t)out_size * sizeof(float), stream);
    // grid: 4(head) * 2(b) * 12(xt) * 6(yt) * 6(zt) = 3456 blocks of 256 threads
    mov3d_kernel<<<3456, 256, 0, stream>>>(xq, xk, out);
}

// Round 11
// 60.369 us; speedup vs baseline: 1.1939x; 1.1939x over previous
//
#include <hip/hip_runtime.h>

// MoV3D: 3D local attention, window +-2 (125 offsets), B=2 C=32 H=W=D=48, 4 heads x 8 ch.
// ROUND 11 = round-10 structure + XCD-chunked blockIdx swizzle (T1).
// Tile (4x,8y,8z), 1 voxel/thread, 256 threads. Halo 8x12x12 = 1152 LDS lines (16B =
// all 8 head channels, fp16 pairs) = 18 KB -> 8 blocks/CU (launch_bounds(256,8)).
// Swizzle: wg = (bid%8)*432 + bid/8 (bijective, 3456 = 8*432). Each XCD gets one
// contiguous (h,b) range; that range's k channel-set is 8ch*110592*4B = 3.5 MB -> fits
// the XCD's 4 MB L2, so halo re-reads (r10: FETCH 180 MB = 3x input, L2-miss) become
// L2 hits instead of ~500cy L3 round-trips.
// Line = lx*144 + lz*12 + ly: ly coeff 1 -> stride-8 lane phases hit 8 distinct bank
// groups -> conflict-free b128 reads (r8-verified; r10: 166K conflicts).
// Scores via v_dot2_f32_f16, log2 domain -> 1-instr exp2; z-validity folded into the
// dot-chain seed (0 / -16384 -> exp2==0 == reference -1000 underflow); xy-mask on
// aggregates. Staged addresses only need IN-BOUNDS (flat clamp).
// RULE-#20: no local arrays; every per-thread value is a named scalar.

#define S_PLANE 2304      // 48*48
#define S_CHAN 110592     // 48*48*48
#define TOTAL  7077888    // 2*32*S_CHAN

typedef _Float16 h2 __attribute__((ext_vector_type(2)));

__device__ __forceinline__ float dot2(h2 a, h2 b, float c) {
#if __has_builtin(__builtin_amdgcn_fdot2)
    return __builtin_amdgcn_fdot2(a, b, c, false);
#else
    return fmaf((float)a[0], (float)b[0], fmaf((float)a[1], (float)b[1], c));
#endif
}

__device__ __forceinline__ h2 bc(unsigned w) { return __builtin_bit_cast(h2, w); }
__device__ __forceinline__ unsigned pk(float a, float b) {
    return __builtin_bit_cast(unsigned, h2{(_Float16)a, (_Float16)b});
}

__global__ __launch_bounds__(256, 8) void mov3d_kernel(
    const float* __restrict__ xq, const float* __restrict__ xk,
    float* __restrict__ out)
{
    __shared__ __align__(16) unsigned kw[4608];   // 1152 lines * 16 B = 18 KB

    const int tid = threadIdx.x;
    const int tz8 = tid & 7;          // z within tile
    const int ty = (tid >> 3) & 7;    // y within tile
    const int tx = tid >> 6;          // x within tile (wave index)

    // XCD-chunked swizzle: 3456 blocks, 8 XCDs, 432 per chunk (bijective).
    // Chunk = contiguous decode range = all tiles of one (h,b)-half -> k-set 3.5 MB/L2.
    const int bid = blockIdx.x;
    int blk = (bid & 7) * 432 + (bid >> 3);

    const int h = blk / 864;
    int rem = blk - h * 864;
    const int zt = rem % 6;  rem /= 6;
    const int yt = rem % 6;  rem /= 6;
    const int xt = rem % 12;
    const int b  = rem / 12;

    const int x0 = xt * 4, y0 = yt * 8, z0 = zt * 8;
    const int x = x0 + tx, y = y0 + ty, z = z0 + tz8;
    const unsigned sp = (unsigned)(x * S_PLANE + y * 48 + z);
    const int bbase = b * (32 * S_CHAN);

    // hd^-0.5 * log2(e): scores in log2 domain
    const float QSCALE = 0.35355339059327373f * 1.4426950408889634f;

    // ---- q: 8 channels (c = 4k+h) at this voxel; pack into 4 fp16 pairs ----
    const float qf0 = xq[(unsigned)(bbase + (h     ) * S_CHAN) + sp];
    const float qf1 = xq[(unsigned)(bbase + (h +  4) * S_CHAN) + sp];
    const float qf2 = xq[(unsigned)(bbase + (h +  8) * S_CHAN) + sp];
    const float qf3 = xq[(unsigned)(bbase + (h + 12) * S_CHAN) + sp];
    const float qf4 = xq[(unsigned)(bbase + (h + 16) * S_CHAN) + sp];
    const float qf5 = xq[(unsigned)(bbase + (h + 20) * S_CHAN) + sp];
    const float qf6 = xq[(unsigned)(bbase + (h + 24) * S_CHAN) + sp];
    const float qf7 = xq[(unsigned)(bbase + (h + 28) * S_CHAN) + sp];
    const h2 qA0 = h2{(_Float16)(qf0 * QSCALE), (_Float16)(qf1 * QSCALE)};
    const h2 qA1 = h2{(_Float16)(qf2 * QSCALE), (_Float16)(qf3 * QSCALE)};
    const h2 qA2 = h2{(_Float16)(qf4 * QSCALE), (_Float16)(qf5 * QSCALE)};
    const h2 qA3 = h2{(_Float16)(qf6 * QSCALE), (_Float16)(qf7 * QSCALE)};

    // ---- stage K halo: thread u covers z-pair (2*lz2, 2*lz2+1) at (lx,ly) ----
    // u in [0,576): lx = u/72, r = u%72, lz2 = r/12, ly = r%12
    // writes lines L0 = lx*144 + lz2*24 + ly (lz even) and L0+12 (lz odd)
    const int sBase = bbase + h * S_CHAN;
#define STAGE_GROUP(G) do {                                                   \
        const int u = (G) * 256 + tid;                                        \
        if ((G) < 2 || tid < 64) {                                            \
            const int lx  = u / 72;                                           \
            const int r   = u - lx * 72;                                      \
            const int lz2 = r / 12;                                           \
            const int ly  = r - lz2 * 12;                                     \
            const int f = sBase + (x0 - 2 + lx) * S_PLANE                     \
                        + (y0 - 2 + ly) * 48 + (z0 - 2 + 2 * lz2);            \
            const int a0 = min(max(f,               0), TOTAL - 2);           \
            const int a1 = min(max(f +  8 * S_CHAN, 0), TOTAL - 2);           \
            const int a2 = min(max(f + 16 * S_CHAN, 0), TOTAL - 2);           \
            const int a3 = min(max(f + 24 * S_CHAN, 0), TOTAL - 2);           \
            const int c0 = min(max(f +  4 * S_CHAN, 0), TOTAL - 2);           \
            const int c1 = min(max(f + 12 * S_CHAN, 0), TOTAL - 2);           \
            const int c2 = min(max(f + 20 * S_CHAN, 0), TOTAL - 2);           \
            const int c3 = min(max(f + 28 * S_CHAN, 0), TOTAL - 2);           \
            const float2 vA0 = *(const float2*)&xk[a0];                       \
            const float2 vA1 = *(const float2*)&xk[a1];                       \
            const float2 vA2 = *(const float2*)&xk[a2];                       \
            const float2 vA3 = *(const float2*)&xk[a3];                       \
            const float2 vB0 = *(const float2*)&xk[c0];                       \
            const float2 vB1 = *(const float2*)&xk[c1];                       \
            const float2 vB2 = *(const float2*)&xk[c2];                       \
            const float2 vB3 = *(const float2*)&xk[c3];                       \
            const uint4 W0 = {pk(vA0.x, vB0.x), pk(vA1.x, vB1.x),             \
                              pk(vA2.x, vB2.x), pk(vA3.x, vB3.x)};            \
            const uint4 W1 = {pk(vA0.y, vB0.y), pk(vA1.y, vB1.y),             \
                              pk(vA2.y, vB2.y), pk(vA3.y, vB3.y)};            \
            const int L0 = lx * 144 + lz2 * 24 + ly;                          \
            *(uint4*)&kw[L0 * 4] = W0;                                        \
            *(uint4*)&kw[(L0 + 12) * 4] = W1;                                 \
        }                                                                     \
    } while (0)
    STAGE_GROUP(0);
    STAGE_GROUP(1);
    STAGE_GROUP(2);
#undef STAGE_GROUP
    __syncthreads();   // single barrier

    // z-validity seeds: slot U covers abs z-2+U; invalid -> exp2(dot-16384) == 0
    const float NEG = -16384.f;
    const float zs0 = ((unsigned)(z - 2) < 48u) ? 0.f : NEG;
    const float zs1 = ((unsigned)(z - 1) < 48u) ? 0.f : NEG;
    const float zs2 = 0.f;                           // z in [0,48)
    const float zs3 = ((unsigned)(z + 1) < 48u) ? 0.f : NEG;
    const float zs4 = ((unsigned)(z + 2) < 48u) ? 0.f : NEG;

    float l = 0.f, ax = 0.f, ay = 0.f, az = 0.f;

#define SCORE(T, SEED) \
    dot2(qA0, bc((T).x), dot2(qA1, bc((T).y), dot2(qA2, bc((T).z), dot2(qA3, bc((T).w), (SEED)))))

    __builtin_amdgcn_s_setprio(1);
#pragma unroll
    for (int dx = -2; dx <= 2; ++dx) {
        const bool vx = (unsigned)(x + dx) < 48u;
        const float fdx = (float)dx;
#pragma unroll
        for (int dy = -2; dy <= 2; ++dy) {
            const bool vxy = vx && ((unsigned)(y + dy) < 48u);
            const float fdy = (float)dy;
            // base line: taps at line m + U*12, U = 0..4 (lz = tz8 + U)
            const unsigned* pb = kw
                + ((tx + 2 + dx) * 144 + tz8 * 12 + (ty + 2 + dy)) * 4;

            const uint4 T0 = *(const uint4*)(pb);
            const uint4 T1 = *(const uint4*)(pb + 48);
            const uint4 T2 = *(const uint4*)(pb + 96);
            const uint4 T3 = *(const uint4*)(pb + 144);
            const uint4 T4 = *(const uint4*)(pb + 192);

            const float e0 = exp2f(SCORE(T0, zs0));
            const float e1 = exp2f(SCORE(T1, zs1));
            const float e2 = exp2f(SCORE(T2, zs2));
            const float e3 = exp2f(SCORE(T3, zs3));
            const float e4 = exp2f(SCORE(T4, zs4));

            float ws  = ((e0 + e1) + (e2 + e3)) + e4;
            float azP = fmaf(2.f, e4 - e0, e3 - e1);

            // xy-mask applied once on the aggregates (shared by all 5 z-taps)
            ws  = vxy ? ws  : 0.f;
            azP = vxy ? azP : 0.f;

            l += ws;
            ax = fmaf(fdx, ws, ax);
            ay = fmaf(fdy, ws, ay);
            az += azP;
        }
    }
    __builtin_amdgcn_s_setprio(0);
#undef SCORE

    const float r = 0.25f / l;
    const unsigned ob = (unsigned)b * (3 * S_CHAN);
    atomicAdd(&out[ob + 0u * S_CHAN + sp], ax * r);
    atomicAdd(&out[ob + 1u * S_CHAN + sp], ay * r);
    atomicAdd(&out[ob + 2u * S_CHAN + sp], az * r);
}

extern "C" void kernel_launch(void* const* d_in, const int* in_sizes, int n_in,
                              void* d_out, int out_size, void* d_ws, size_t ws_size,
                              hipStream_t stream) {
    const float* xq = (const float*)d_in[0];
    const float* xk = (const float*)d_in[1];
    float* out = (float*)d_out;
    // zero output (heads accumulate via atomicAdd); memset node is graph-capturable
    hipMemsetAsync(out, 0, (size_t)out_size * sizeof(float), stream);
    // grid: 4(head) * 2(b) * 12(xt) * 6(yt) * 6(zt) = 3456 blocks of 256 threads
    mov3d_kernel<<<3456, 256, 0, stream>>>(xq, xk, out);
}

// Round 12
// 59.174 us; speedup vs baseline: 1.2181x; 1.0202x over previous
//
#include <hip/hip_runtime.h>

// MoV3D: 3D local attention, window +-2 (125 offsets), B=2 C=32 H=W=D=48, 4 heads x 8 ch.
// ROUND 12 = round-11 structure + VALU trims (cvt_pkrtz staging, single spatial clamp,
// dx-grouped accumulation). Structure unchanged:
//  - Tile (4x,8y,8z), 1 voxel/thread, 256 threads; halo 8x12x12 = 1152 LDS lines = 18 KB
//    -> 8 blocks/CU (launch_bounds(256,8)).
//  - XCD-chunked swizzle wg=(bid%8)*432+bid/8 (r11-verified: FETCH 180->29 MB, L2-resident).
//  - Line = lx*144 + lz*12 + ly (ly coeff 1 -> conflict-free b128, r8-verified).
//  - fp16 channel-pair dot2 (v_dot2_f32_f16), log2-domain scores -> 1-instr exp2;
//    z-validity folded into dot-chain seed (0/-16384 -> exp2==0 == ref -1000 underflow);
//    xy-mask on aggregates. Staged addresses only need IN-BOUNDS (single spatial clamp:
//    srel in [0,S_CHAN-2] => all 8 channel addrs in [0,TOTAL) since sBase+31*S_CHAN+
//    S_CHAN-2 < TOTAL).
// RULE-#20: no local arrays; every per-thread value is a named scalar.

#define S_PLANE 2304      // 48*48
#define S_CHAN 110592     // 48*48*48
#define TOTAL  7077888    // 2*32*S_CHAN

typedef _Float16 h2 __attribute__((ext_vector_type(2)));

__device__ __forceinline__ float dot2(h2 a, h2 b, float c) {
#if __has_builtin(__builtin_amdgcn_fdot2)
    return __builtin_amdgcn_fdot2(a, b, c, false);
#else
    return fmaf((float)a[0], (float)b[0], fmaf((float)a[1], (float)b[1], c));
#endif
}

__device__ __forceinline__ h2 bc(unsigned w) { return __builtin_bit_cast(h2, w); }

// single-instruction pack: v_cvt_pkrtz_f16_f32 (RTZ; k-side only, headroom 3.3x)
__device__ __forceinline__ unsigned pkz(float a, float b) {
#if __has_builtin(__builtin_amdgcn_cvt_pkrtz)
    return __builtin_bit_cast(unsigned, __builtin_amdgcn_cvt_pkrtz(a, b));
#else
    return __builtin_bit_cast(unsigned, h2{(_Float16)a, (_Float16)b});
#endif
}

__global__ __launch_bounds__(256, 8) void mov3d_kernel(
    const float* __restrict__ xq, const float* __restrict__ xk,
    float* __restrict__ out)
{
    __shared__ __align__(16) unsigned kw[4608];   // 1152 lines * 16 B = 18 KB

    const int tid = threadIdx.x;
    const int tz8 = tid & 7;          // z within tile
    const int ty = (tid >> 3) & 7;    // y within tile
    const int tx = tid >> 6;          // x within tile (wave index)

    // XCD-chunked swizzle: 3456 blocks, 8 XCDs, 432 per chunk (bijective).
    const int bid = blockIdx.x;
    int blk = (bid & 7) * 432 + (bid >> 3);

    const int h = blk / 864;
    int rem = blk - h * 864;
    const int zt = rem % 6;  rem /= 6;
    const int yt = rem % 6;  rem /= 6;
    const int xt = rem % 12;
    const int b  = rem / 12;

    const int x0 = xt * 4, y0 = yt * 8, z0 = zt * 8;
    const int x = x0 + tx, y = y0 + ty, z = z0 + tz8;
    const unsigned sp = (unsigned)(x * S_PLANE + y * 48 + z);
    const int bbase = b * (32 * S_CHAN);

    // hd^-0.5 * log2(e): scores in log2 domain
    const float QSCALE = 0.35355339059327373f * 1.4426950408889634f;

    // ---- q: 8 channels (c = 4k+h) at this voxel; pack into 4 fp16 pairs (RNE) ----
    const float qf0 = xq[(unsigned)(bbase + (h     ) * S_CHAN) + sp];
    const float qf1 = xq[(unsigned)(bbase + (h +  4) * S_CHAN) + sp];
    const float qf2 = xq[(unsigned)(bbase + (h +  8) * S_CHAN) + sp];
    const float qf3 = xq[(unsigned)(bbase + (h + 12) * S_CHAN) + sp];
    const float qf4 = xq[(unsigned)(bbase + (h + 16) * S_CHAN) + sp];
    const float qf5 = xq[(unsigned)(bbase + (h + 20) * S_CHAN) + sp];
    const float qf6 = xq[(unsigned)(bbase + (h + 24) * S_CHAN) + sp];
    const float qf7 = xq[(unsigned)(bbase + (h + 28) * S_CHAN) + sp];
    const h2 qA0 = h2{(_Float16)(qf0 * QSCALE), (_Float16)(qf1 * QSCALE)};
    const h2 qA1 = h2{(_Float16)(qf2 * QSCALE), (_Float16)(qf3 * QSCALE)};
    const h2 qA2 = h2{(_Float16)(qf4 * QSCALE), (_Float16)(qf5 * QSCALE)};
    const h2 qA3 = h2{(_Float16)(qf6 * QSCALE), (_Float16)(qf7 * QSCALE)};

    // ---- stage K halo: thread u covers z-pair (2*lz2, 2*lz2+1) at (lx,ly) ----
    const int sBase = bbase + h * S_CHAN;
#define STAGE_GROUP(G) do {                                                   \
        const int u = (G) * 256 + tid;                                        \
        if ((G) < 2 || tid < 64) {                                            \
            const int lx  = u / 72;                                           \
            const int r   = u - lx * 72;                                      \
            const int lz2 = r / 12;                                           \
            const int ly  = r - lz2 * 12;                                     \
            const int srel0 = (x0 - 2 + lx) * S_PLANE                         \
                            + (y0 - 2 + ly) * 48 + (z0 - 2 + 2 * lz2);        \
            const int srel = min(max(srel0, 0), S_CHAN - 2);                  \
            const int f = sBase + srel;   /* all +c*S_CHAN stay in-bounds */  \
            const float2 vA0 = *(const float2*)&xk[f];                        \
            const float2 vA1 = *(const float2*)&xk[f +  8 * S_CHAN];          \
            const float2 vA2 = *(const float2*)&xk[f + 16 * S_CHAN];          \
            const float2 vA3 = *(const float2*)&xk[f + 24 * S_CHAN];          \
            const float2 vB0 = *(const float2*)&xk[f +  4 * S_CHAN];          \
            const float2 vB1 = *(const float2*)&xk[f + 12 * S_CHAN];          \
            const float2 vB2 = *(const float2*)&xk[f + 20 * S_CHAN];          \
            const float2 vB3 = *(const float2*)&xk[f + 28 * S_CHAN];          \
            const uint4 W0 = {pkz(vA0.x, vB0.x), pkz(vA1.x, vB1.x),           \
                              pkz(vA2.x, vB2.x), pkz(vA3.x, vB3.x)};          \
            const uint4 W1 = {pkz(vA0.y, vB0.y), pkz(vA1.y, vB1.y),           \
                              pkz(vA2.y, vB2.y), pkz(vA3.y, vB3.y)};          \
            const int L0 = lx * 144 + lz2 * 24 + ly;                          \
            *(uint4*)&kw[L0 * 4] = W0;                                        \
            *(uint4*)&kw[(L0 + 12) * 4] = W1;                                 \
        }                                                                     \
    } while (0)
    STAGE_GROUP(0);
    STAGE_GROUP(1);
    STAGE_GROUP(2);
#undef STAGE_GROUP
    __syncthreads();   // single barrier

    // z-validity seeds: slot U covers abs z-2+U; invalid -> exp2(dot-16384) == 0
    const float NEG = -16384.f;
    const float zs0 = ((unsigned)(z - 2) < 48u) ? 0.f : NEG;
    const float zs1 = ((unsigned)(z - 1) < 48u) ? 0.f : NEG;
    const float zs2 = 0.f;                           // z in [0,48)
    const float zs3 = ((unsigned)(z + 1) < 48u) ? 0.f : NEG;
    const float zs4 = ((unsigned)(z + 2) < 48u) ? 0.f : NEG;

    float l = 0.f, ax = 0.f, ay = 0.f, az = 0.f;

#define SCORE(T, SEED) \
    dot2(qA0, bc((T).x), dot2(qA1, bc((T).y), dot2(qA2, bc((T).z), dot2(qA3, bc((T).w), (SEED)))))

    __builtin_amdgcn_s_setprio(1);
#pragma unroll
    for (int dx = -2; dx <= 2; ++dx) {
        const bool vx = (unsigned)(x + dx) < 48u;
        const float fdx = (float)dx;
        float wsdx = 0.f;                 // dx-slice weight subtotal (ax,l folded at end)
#pragma unroll
        for (int dy = -2; dy <= 2; ++dy) {
            const bool vxy = vx && ((unsigned)(y + dy) < 48u);
            const float fdy = (float)dy;
            // base line: taps at line m + U*12, U = 0..4 (lz = tz8 + U)
            const unsigned* pb = kw
                + ((tx + 2 + dx) * 144 + tz8 * 12 + (ty + 2 + dy)) * 4;

            const uint4 T0 = *(const uint4*)(pb);
            const uint4 T1 = *(const uint4*)(pb + 48);
            const uint4 T2 = *(const uint4*)(pb + 96);
            const uint4 T3 = *(const uint4*)(pb + 144);
            const uint4 T4 = *(const uint4*)(pb + 192);

            const float e0 = exp2f(SCORE(T0, zs0));
            const float e1 = exp2f(SCORE(T1, zs1));
            const float e2 = exp2f(SCORE(T2, zs2));
            const float e3 = exp2f(SCORE(T3, zs3));
            const float e4 = exp2f(SCORE(T4, zs4));

            float ws  = ((e0 + e1) + (e2 + e3)) + e4;
            float azP = fmaf(2.f, e4 - e0, e3 - e1);

            // xy-mask applied once on the aggregates (shared by all 5 z-taps)
            ws  = vxy ? ws  : 0.f;
            azP = vxy ? azP : 0.f;

            wsdx += ws;
            ay = fmaf(fdy, ws, ay);
            az += azP;
        }
        ax = fmaf(fdx, wsdx, ax);
        l += wsdx;
    }
    __builtin_amdgcn_s_setprio(0);
#undef SCORE

    const float r = 0.25f / l;
    const unsigned ob = (unsigned)b * (3 * S_CHAN);
    atomicAdd(&out[ob + 0u * S_CHAN + sp], ax * r);
    atomicAdd(&out[ob + 1u * S_CHAN + sp], ay * r);
    atomicAdd(&out[ob + 2u * S_CHAN + sp], az * r);
}

extern "C" void kernel_launch(void* const* d_in, const int* in_sizes, int n_in,
                              void* d_out, int out_size, void* d_ws, size_t ws_size,
                              hipStream_t stream) {
    const float* xq = (const float*)d_in[0];
    const float* xk = (const float*)d_in[1];
    float* out = (float*)d_out;
    // zero output (heads accumulate via atomicAdd); memset node is graph-capturable
    hipMemsetAsync(out, 0, (size_t)out_size * sizeof(float), stream);
    // grid: 4(head) * 2(b) * 12(xt) * 6(yt) * 6(zt) = 3456 blocks of 256 threads
    mov3d_kernel<<<3456, 256, 0, stream>>>(xq, xk, out);
}

// Round 13
// 50.622 us; speedup vs baseline: 1.4238x; 1.1689x over previous
//
#include <hip/hip_runtime.h>

// MoV3D: 3D local attention, window +-2 (125 offsets), B=2 C=32 H=W=D=48, 4 heads x 8 ch.
// ROUND 13 = round-12 + ONE change: exp2f -> __builtin_amdgcn_exp2f (bare v_exp_f32).
// Rationale: measured VALU-busy (~45us/CU) is ~2.5x the instruction-count estimate;
// prime suspect is OCML exp2f edge-handling (125 calls/thread). Domain safe: scores in
// [-16384, ~50], v_exp_f32(-16384) == 0 exactly (preserves OOB masking semantics).
// Structure unchanged from r12:
//  - Tile (4x,8y,8z), 1 voxel/thread, 256 threads; halo 8x12x12 = 1152 LDS lines = 18 KB
//    -> 8 blocks/CU (launch_bounds(256,8)).
//  - XCD-chunked swizzle wg=(bid%8)*432+bid/8 (r11: FETCH 180->29 MB, L2-resident).
//  - Line = lx*144 + lz*12 + ly (ly coeff 1 -> conflict-free b128, r8-verified).
//  - fp16 channel-pair dot2 (v_dot2_f32_f16), log2-domain scores; z-validity folded
//    into dot-chain seed (0/-16384); xy-mask on aggregates; single spatial clamp;
//    cvt_pkrtz staging pack; dx-grouped accumulation.
// RULE-#20: no local arrays; every per-thread value is a named scalar.

#define S_PLANE 2304      // 48*48
#define S_CHAN 110592     // 48*48*48
#define TOTAL  7077888    // 2*32*S_CHAN

typedef _Float16 h2 __attribute__((ext_vector_type(2)));

__device__ __forceinline__ float dot2(h2 a, h2 b, float c) {
#if __has_builtin(__builtin_amdgcn_fdot2)
    return __builtin_amdgcn_fdot2(a, b, c, false);
#else
    return fmaf((float)a[0], (float)b[0], fmaf((float)a[1], (float)b[1], c));
#endif
}

// bare v_exp_f32 (2^x), no OCML edge-handling
__device__ __forceinline__ float fexp2(float x) {
#if __has_builtin(__builtin_amdgcn_exp2f)
    return __builtin_amdgcn_exp2f(x);
#else
    return __exp2f(x);
#endif
}

__device__ __forceinline__ h2 bc(unsigned w) { return __builtin_bit_cast(h2, w); }

// single-instruction pack: v_cvt_pkrtz_f16_f32 (RTZ; k-side only, headroom 3.3x)
__device__ __forceinline__ unsigned pkz(float a, float b) {
#if __has_builtin(__builtin_amdgcn_cvt_pkrtz)
    return __builtin_bit_cast(unsigned, __builtin_amdgcn_cvt_pkrtz(a, b));
#else
    return __builtin_bit_cast(unsigned, h2{(_Float16)a, (_Float16)b});
#endif
}

__global__ __launch_bounds__(256, 8) void mov3d_kernel(
    const float* __restrict__ xq, const float* __restrict__ xk,
    float* __restrict__ out)
{
    __shared__ __align__(16) unsigned kw[4608];   // 1152 lines * 16 B = 18 KB

    const int tid = threadIdx.x;
    const int tz8 = tid & 7;          // z within tile
    const int ty = (tid >> 3) & 7;    // y within tile
    const int tx = tid >> 6;          // x within tile (wave index)

    // XCD-chunked swizzle: 3456 blocks, 8 XCDs, 432 per chunk (bijective).
    const int bid = blockIdx.x;
    int blk = (bid & 7) * 432 + (bid >> 3);

    const int h = blk / 864;
    int rem = blk - h * 864;
    const int zt = rem % 6;  rem /= 6;
    const int yt = rem % 6;  rem /= 6;
    const int xt = rem % 12;
    const int b  = rem / 12;

    const int x0 = xt * 4, y0 = yt * 8, z0 = zt * 8;
    const int x = x0 + tx, y = y0 + ty, z = z0 + tz8;
    const unsigned sp = (unsigned)(x * S_PLANE + y * 48 + z);
    const int bbase = b * (32 * S_CHAN);

    // hd^-0.5 * log2(e): scores in log2 domain
    const float QSCALE = 0.35355339059327373f * 1.4426950408889634f;

    // ---- q: 8 channels (c = 4k+h) at this voxel; pack into 4 fp16 pairs (RNE) ----
    const float qf0 = xq[(unsigned)(bbase + (h     ) * S_CHAN) + sp];
    const float qf1 = xq[(unsigned)(bbase + (h +  4) * S_CHAN) + sp];
    const float qf2 = xq[(unsigned)(bbase + (h +  8) * S_CHAN) + sp];
    const float qf3 = xq[(unsigned)(bbase + (h + 12) * S_CHAN) + sp];
    const float qf4 = xq[(unsigned)(bbase + (h + 16) * S_CHAN) + sp];
    const float qf5 = xq[(unsigned)(bbase + (h + 20) * S_CHAN) + sp];
    const float qf6 = xq[(unsigned)(bbase + (h + 24) * S_CHAN) + sp];
    const float qf7 = xq[(unsigned)(bbase + (h + 28) * S_CHAN) + sp];
    const h2 qA0 = h2{(_Float16)(qf0 * QSCALE), (_Float16)(qf1 * QSCALE)};
    const h2 qA1 = h2{(_Float16)(qf2 * QSCALE), (_Float16)(qf3 * QSCALE)};
    const h2 qA2 = h2{(_Float16)(qf4 * QSCALE), (_Float16)(qf5 * QSCALE)};
    const h2 qA3 = h2{(_Float16)(qf6 * QSCALE), (_Float16)(qf7 * QSCALE)};

    // ---- stage K halo: thread u covers z-pair (2*lz2, 2*lz2+1) at (lx,ly) ----
    const int sBase = bbase + h * S_CHAN;
#define STAGE_GROUP(G) do {                                                   \
        const int u = (G) * 256 + tid;                                        \
        if ((G) < 2 || tid < 64) {                                            \
            const int lx  = u / 72;                                           \
            const int r   = u - lx * 72;                                      \
            const int lz2 = r / 12;                                           \
            const int ly  = r - lz2 * 12;                                     \
            const int srel0 = (x0 - 2 + lx) * S_PLANE                         \
                            + (y0 - 2 + ly) * 48 + (z0 - 2 + 2 * lz2);        \
            const int srel = min(max(srel0, 0), S_CHAN - 2);                  \
            const int f = sBase + srel;   /* all +c*S_CHAN stay in-bounds */  \
            const float2 vA0 = *(const float2*)&xk[f];                        \
            const float2 vA1 = *(const float2*)&xk[f +  8 * S_CHAN];          \
            const float2 vA2 = *(const float2*)&xk[f + 16 * S_CHAN];          \
            const float2 vA3 = *(const float2*)&xk[f + 24 * S_CHAN];          \
            const float2 vB0 = *(const float2*)&xk[f +  4 * S_CHAN];          \
            const float2 vB1 = *(const float2*)&xk[f + 12 * S_CHAN];          \
            const float2 vB2 = *(const float2*)&xk[f + 20 * S_CHAN];          \
            const float2 vB3 = *(const float2*)&xk[f + 28 * S_CHAN];          \
            const uint4 W0 = {pkz(vA0.x, vB0.x), pkz(vA1.x, vB1.x),           \
                              pkz(vA2.x, vB2.x), pkz(vA3.x, vB3.x)};          \
            const uint4 W1 = {pkz(vA0.y, vB0.y), pkz(vA1.y, vB1.y),           \
                              pkz(vA2.y, vB2.y), pkz(vA3.y, vB3.y)};          \
            const int L0 = lx * 144 + lz2 * 24 + ly;                          \
            *(uint4*)&kw[L0 * 4] = W0;                                        \
            *(uint4*)&kw[(L0 + 12) * 4] = W1;                                 \
        }                                                                     \
    } while (0)
    STAGE_GROUP(0);
    STAGE_GROUP(1);
    STAGE_GROUP(2);
#undef STAGE_GROUP
    __syncthreads();   // single barrier

    // z-validity seeds: slot U covers abs z-2+U; invalid -> exp2(dot-16384) == 0
    const float NEG = -16384.f;
    const float zs0 = ((unsigned)(z - 2) < 48u) ? 0.f : NEG;
    const float zs1 = ((unsigned)(z - 1) < 48u) ? 0.f : NEG;
    const float zs2 = 0.f;                           // z in [0,48)
    const float zs3 = ((unsigned)(z + 1) < 48u) ? 0.f : NEG;
    const float zs4 = ((unsigned)(z + 2) < 48u) ? 0.f : NEG;

    float l = 0.f, ax = 0.f, ay = 0.f, az = 0.f;

#define SCORE(T, SEED) \
    dot2(qA0, bc((T).x), dot2(qA1, bc((T).y), dot2(qA2, bc((T).z), dot2(qA3, bc((T).w), (SEED)))))

    __builtin_amdgcn_s_setprio(1);
#pragma unroll
    for (int dx = -2; dx <= 2; ++dx) {
        const bool vx = (unsigned)(x + dx) < 48u;
        const float fdx = (float)dx;
        float wsdx = 0.f;                 // dx-slice weight subtotal (ax,l folded at end)
#pragma unroll
        for (int dy = -2; dy <= 2; ++dy) {
            const bool vxy = vx && ((unsigned)(y + dy) < 48u);
            const float fdy = (float)dy;
            // base line: taps at line m + U*12, U = 0..4 (lz = tz8 + U)
            const unsigned* pb = kw
                + ((tx + 2 + dx) * 144 + tz8 * 12 + (ty + 2 + dy)) * 4;

            const uint4 T0 = *(const uint4*)(pb);
            const uint4 T1 = *(const uint4*)(pb + 48);
            const uint4 T2 = *(const uint4*)(pb + 96);
            const uint4 T3 = *(const uint4*)(pb + 144);
            const uint4 T4 = *(const uint4*)(pb + 192);

            const float e0 = fexp2(SCORE(T0, zs0));
            const float e1 = fexp2(SCORE(T1, zs1));
            const float e2 = fexp2(SCORE(T2, zs2));
            const float e3 = fexp2(SCORE(T3, zs3));
            const float e4 = fexp2(SCORE(T4, zs4));

            float ws  = ((e0 + e1) + (e2 + e3)) + e4;
            float azP = fmaf(2.f, e4 - e0, e3 - e1);

            // xy-mask applied once on the aggregates (shared by all 5 z-taps)
            ws  = vxy ? ws  : 0.f;
            azP = vxy ? azP : 0.f;

            wsdx += ws;
            ay = fmaf(fdy, ws, ay);
            az += azP;
        }
        ax = fmaf(fdx, wsdx, ax);
        l += wsdx;
    }
    __builtin_amdgcn_s_setprio(0);
#undef SCORE

    const float r = 0.25f / l;
    const unsigned ob = (unsigned)b * (3 * S_CHAN);
    atomicAdd(&out[ob + 0u * S_CHAN + sp], ax * r);
    atomicAdd(&out[ob + 1u * S_CHAN + sp], ay * r);
    atomicAdd(&out[ob + 2u * S_CHAN + sp], az * r);
}

extern "C" void kernel_launch(void* const* d_in, const int* in_sizes, int n_in,
                              void* d_out, int out_size, void* d_ws, size_t ws_size,
                              hipStream_t stream) {
    const float* xq = (const float*)d_in[0];
    const float* xk = (const float*)d_in[1];
    float* out = (float*)d_out;
    // zero output (heads accumulate via atomicAdd); memset node is graph-capturable
    hipMemsetAsync(out, 0, (size_t)out_size * sizeof(float), stream);
    // grid: 4(head) * 2(b) * 12(xt) * 6(yt) * 6(zt) = 3456 blocks of 256 threads
    mov3d_kernel<<<3456, 256, 0, stream>>>(xq, xk, out);
}